// Round 1
// baseline (800.399 us; speedup 1.0000x reference)
//
#include <hip/hip_runtime.h>
#include <math.h>

#define FLAT 12288
#define NH 4096
#define KSTEPS 4
#define LRC 0.01f
#define NSEG 96
#define ROWS_PER_SEG 128   // NSEG * ROWS_PER_SEG == FLAT

__device__ __forceinline__ float sigm(float x) { return 1.0f / (1.0f + expf(-x)); }

// ---------------- Phase A: dense sample-0 kernels ----------------

// partials[seg][j] = sum_{r in seg} W[r][j] * v[r]   (W row-major FLAT x NH)
// grid (4, NSEG), block 256. Each thread owns 4 consecutive columns (float4).
__global__ __launch_bounds__(256) void k_colpart(const float* __restrict__ W,
                                                 const float* __restrict__ v,
                                                 float* __restrict__ partials) {
    const float4* W4 = (const float4*)W;
    int c4 = blockIdx.x * 256 + threadIdx.x;          // float4 column index [0,1024)
    int r0 = blockIdx.y * ROWS_PER_SEG;
    float4 acc = make_float4(0.f, 0.f, 0.f, 0.f);
    for (int r = r0; r < r0 + ROWS_PER_SEG; ++r) {
        float vr = v[r];                               // uniform -> scalar load
        float4 w = W4[(size_t)r * (NH / 4) + c4];
        acc.x = fmaf(w.x, vr, acc.x);
        acc.y = fmaf(w.y, vr, acc.y);
        acc.z = fmaf(w.z, vr, acc.z);
        acc.w = fmaf(w.w, vr, acc.w);
    }
    ((float4*)partials)[(size_t)blockIdx.y * (NH / 4) + c4] = acc;
}

// h[j] = sigm(b[j] + sum_seg partials[seg][j]); optionally also save to hi.
__global__ __launch_bounds__(256) void k_hreduce(const float* __restrict__ partials,
                                                 const float* __restrict__ b,
                                                 float* __restrict__ h,
                                                 float* __restrict__ hi) {
    int j = blockIdx.x * 256 + threadIdx.x;
    float s = 0.f;
    for (int g = 0; g < NSEG; ++g) s += partials[(size_t)g * NH + j];
    float hh = sigm(s + b[j]);
    h[j] = hh;
    if (hi) hi[j] = hh;
}

// v[row] = sigm(a[row] + W[row,:] . h). One wave (64 lanes) per row.
__global__ __launch_bounds__(256) void k_vstep(const float* __restrict__ W,
                                               const float* __restrict__ h,
                                               const float* __restrict__ a,
                                               float* __restrict__ v) {
    int wid = threadIdx.x >> 6;
    int lane = threadIdx.x & 63;
    int row = blockIdx.x * 4 + wid;
    const float4* Wr = (const float4*)(W + (size_t)row * NH);
    const float4* h4 = (const float4*)h;
    float acc = 0.f;
    for (int k = lane; k < NH / 4; k += 64) {
        float4 w = Wr[k];
        float4 hh = h4[k];
        acc = fmaf(w.x, hh.x, fmaf(w.y, hh.y, fmaf(w.z, hh.z, fmaf(w.w, hh.w, acc))));
    }
    for (int off = 32; off; off >>= 1) acc += __shfl_down(acc, off);
    if (lane == 0) v[row] = sigm(a[row] + acc);
}

// ---------------- Phase B: samples 1..15 with rank-2 W ----------------

#define TPB 1024
#define RV (FLAT / TPB)   // 12
#define RH (NH / TPB)     // 4

__global__ __launch_bounds__(1024) void k_phaseB(const float* __restrict__ inputs,
                                                 const float* __restrict__ hi0,
                                                 const float* __restrict__ hk0,
                                                 const float* __restrict__ vk0,
                                                 float* __restrict__ out) {
    int t = threadIdx.x;
    int lane = t & 63;
    int wid = t >> 6;
    __shared__ float red[2][16];
    __shared__ float bc[2];

    float Vi[RV], Vk[RV], v[RV];
    float Hi[RH], Hk[RH], h[RH], hini[RH];

#pragma unroll
    for (int r = 0; r < RV; r++) { int i = r * TPB + t; Vi[r] = inputs[i]; Vk[r] = vk0[i]; }
#pragma unroll
    for (int r = 0; r < RH; r++) { int j = r * TPB + t; Hi[r] = hi0[j]; Hk[r] = hk0[j]; }

    for (int s = 1; s < 16; ++s) {
        const float* vin = inputs + (size_t)s * FLAT;
#pragma unroll
        for (int r = 0; r < RV; r++) v[r] = vin[r * TPB + t];

        for (int k = 0; k < KSTEPS; ++k) {
            // alpha = Vi.v, beta = Vk.v
            float px = 0.f, py = 0.f;
#pragma unroll
            for (int r = 0; r < RV; r++) { px = fmaf(Vi[r], v[r], px); py = fmaf(Vk[r], v[r], py); }
            for (int off = 32; off; off >>= 1) { px += __shfl_down(px, off); py += __shfl_down(py, off); }
            if (lane == 0) { red[0][wid] = px; red[1][wid] = py; }
            __syncthreads();
            if (t == 0) {
                float sx = 0.f, sy = 0.f;
                for (int w = 0; w < 16; w++) { sx += red[0][w]; sy += red[1][w]; }
                bc[0] = sx; bc[1] = sy;
            }
            __syncthreads();
            float alpha = bc[0], beta = bc[1];

            // h = sigm(b + LR*(alpha*Hi - beta*Hk)), b = LR*(Hi - Hk)
#pragma unroll
            for (int r = 0; r < RH; r++) {
                float bb = LRC * (Hi[r] - Hk[r]);
                float hh = sigm(bb + LRC * (alpha * Hi[r] - beta * Hk[r]));
                h[r] = hh;
                if (k == 0) hini[r] = hh;
            }

            // gamma = Hi.h, delta = Hk.h
            px = 0.f; py = 0.f;
#pragma unroll
            for (int r = 0; r < RH; r++) { px = fmaf(Hi[r], h[r], px); py = fmaf(Hk[r], h[r], py); }
            for (int off = 32; off; off >>= 1) { px += __shfl_down(px, off); py += __shfl_down(py, off); }
            if (lane == 0) { red[0][wid] = px; red[1][wid] = py; }
            __syncthreads();
            if (t == 0) {
                float sx = 0.f, sy = 0.f;
                for (int w = 0; w < 16; w++) { sx += red[0][w]; sy += red[1][w]; }
                bc[0] = sx; bc[1] = sy;
            }
            __syncthreads();
            float gamma = bc[0], delta = bc[1];

            // v = sigm(a + LR*(gamma*Vi - delta*Vk)), a = LR*(Vi - Vk)
#pragma unroll
            for (int r = 0; r < RV; r++) {
                float aa = LRC * (Vi[r] - Vk[r]);
                v[r] = sigm(aa + LRC * (gamma * Vi[r] - delta * Vk[r]));
            }
        }

        // rotate carry: Vi <- inputs[s], Vk <- v, Hi <- h_init, Hk <- h
#pragma unroll
        for (int r = 0; r < RV; r++) { Vk[r] = v[r]; Vi[r] = vin[r * TPB + t]; }
#pragma unroll
        for (int r = 0; r < RH; r++) { Hk[r] = h[r]; Hi[r] = hini[r]; }
    }

#pragma unroll
    for (int r = 0; r < RV; r++) out[r * TPB + t] = Vk[r];
}

// ---------------- launch ----------------

extern "C" void kernel_launch(void* const* d_in, const int* in_sizes, int n_in,
                              void* d_out, int out_size, void* d_ws, size_t ws_size,
                              hipStream_t stream) {
    const float* inputs = (const float*)d_in[0];   // 16*12288
    const float* W      = (const float*)d_in[1];   // 12288*4096
    const float* a_in   = (const float*)d_in[2];   // 12288
    const float* b_in   = (const float*)d_in[3];   // 4096
    float* out = (float*)d_out;                    // 12288

    float* ws = (float*)d_ws;
    float* partials = ws;                          // NSEG*NH
    float* h  = partials + (size_t)NSEG * NH;      // NH
    float* hi = h + NH;                            // NH
    float* v  = hi + NH;                           // FLAT

    dim3 cgrid(4, NSEG), blk(256);

    // Sample 0, Gibbs step 1 (h1 == h_init -> save to hi)
    k_colpart<<<cgrid, blk, 0, stream>>>(W, inputs, partials);
    k_hreduce<<<dim3(NH / 256), blk, 0, stream>>>(partials, b_in, h, hi);
    k_vstep<<<dim3(FLAT / 4), blk, 0, stream>>>(W, h, a_in, v);

    // Gibbs steps 2..4
    for (int k = 1; k < KSTEPS; ++k) {
        k_colpart<<<cgrid, blk, 0, stream>>>(W, v, partials);
        k_hreduce<<<dim3(NH / 256), blk, 0, stream>>>(partials, b_in, h, (float*)nullptr);
        k_vstep<<<dim3(FLAT / 4), blk, 0, stream>>>(W, h, a_in, v);
    }

    // Samples 1..15 (rank-2 W), writes final reconstruction
    k_phaseB<<<1, TPB, 0, stream>>>(inputs, hi, h, v, out);
}

// Round 3
// 547.667 us; speedup vs baseline: 1.4615x; 1.4615x over previous
//
#include <hip/hip_runtime.h>
#include <math.h>

#define FLAT 12288
#define NH   4096
#define KSTEPS 4
#define LRC 0.01f
#define NSEG 192
#define RPS  64       // rows per segment; NSEG*RPS == FLAT

__device__ __forceinline__ float sigm(float x) {
    return __builtin_amdgcn_rcpf(1.0f + __expf(-x));
}

__device__ __forceinline__ unsigned short f2bf(float f) {   // round-to-nearest-even
    unsigned u = __float_as_uint(f);
    unsigned r = u + 0x7FFFu + ((u >> 16) & 1u);
    return (unsigned short)(r >> 16);
}
__device__ __forceinline__ float bflo(unsigned w) { return __uint_as_float(w << 16); }
__device__ __forceinline__ float bfhi(unsigned w) { return __uint_as_float(w & 0xFFFF0000u); }

// ---- DPP wave64 sum: result valid in lane 63 ----
template <int CTRL>
__device__ __forceinline__ float dpp_add(float x) {
    int s = __builtin_amdgcn_update_dpp(0, __float_as_int(x), CTRL, 0xf, 0xf, true);
    return x + __int_as_float(s);
}
__device__ __forceinline__ float wave_sum63(float x) {
    x = dpp_add<0x111>(x);  // row_shr:1
    x = dpp_add<0x112>(x);  // row_shr:2
    x = dpp_add<0x114>(x);  // row_shr:4
    x = dpp_add<0x118>(x);  // row_shr:8
    x = dpp_add<0x142>(x);  // row_bcast:15
    x = dpp_add<0x143>(x);  // row_bcast:31
    return x;               // lane 63 holds the full sum
}

// ================= Phase A =================

// fp32 W pass 0: partials + convert W -> bf16. grid (4, NSEG), block 256.
__global__ __launch_bounds__(256) void k_colpart_cvt(const float* __restrict__ W,
                                                     const float* __restrict__ v,
                                                     float* __restrict__ partials,
                                                     unsigned short* __restrict__ Wbf) {
    const float4* W4 = (const float4*)W;
    int c4 = blockIdx.x * 256 + threadIdx.x;           // [0,1024)
    int r0 = blockIdx.y * RPS;
    float4 acc = make_float4(0.f, 0.f, 0.f, 0.f);
    for (int r = r0; r < r0 + RPS; ++r) {
        float vr = v[r];
        float4 w = W4[(size_t)r * (NH / 4) + c4];
        acc.x = fmaf(w.x, vr, acc.x);
        acc.y = fmaf(w.y, vr, acc.y);
        acc.z = fmaf(w.z, vr, acc.z);
        acc.w = fmaf(w.w, vr, acc.w);
        ushort4 bw;
        bw.x = f2bf(w.x); bw.y = f2bf(w.y); bw.z = f2bf(w.z); bw.w = f2bf(w.w);
        ((ushort4*)Wbf)[(size_t)r * (NH / 4) + c4] = bw;
    }
    ((float4*)partials)[(size_t)blockIdx.y * (NH / 4) + c4] = acc;
}

// fp32 fallback colpart. grid (4, NSEG), block 256.
__global__ __launch_bounds__(256) void k_colpart_f32(const float* __restrict__ W,
                                                     const float* __restrict__ v,
                                                     float* __restrict__ partials) {
    const float4* W4 = (const float4*)W;
    int c4 = blockIdx.x * 256 + threadIdx.x;
    int r0 = blockIdx.y * RPS;
    float4 acc = make_float4(0.f, 0.f, 0.f, 0.f);
    for (int r = r0; r < r0 + RPS; ++r) {
        float vr = v[r];
        float4 w = W4[(size_t)r * (NH / 4) + c4];
        acc.x = fmaf(w.x, vr, acc.x);
        acc.y = fmaf(w.y, vr, acc.y);
        acc.z = fmaf(w.z, vr, acc.z);
        acc.w = fmaf(w.w, vr, acc.w);
    }
    ((float4*)partials)[(size_t)blockIdx.y * (NH / 4) + c4] = acc;
}

// bf16 colpart: 8 cols/thread. grid (2, NSEG), block 256.
__global__ __launch_bounds__(256) void k_colpart_bf(const unsigned short* __restrict__ Wbf,
                                                    const float* __restrict__ v,
                                                    float* __restrict__ partials) {
    const uint4* W8 = (const uint4*)Wbf;
    int c8 = blockIdx.x * 256 + threadIdx.x;           // [0,512)
    int r0 = blockIdx.y * RPS;
    float a0=0,a1=0,a2=0,a3=0,a4=0,a5=0,a6=0,a7=0;
    for (int r = r0; r < r0 + RPS; ++r) {
        float vr = v[r];
        uint4 w = W8[(size_t)r * (NH / 8) + c8];
        a0 = fmaf(bflo(w.x), vr, a0); a1 = fmaf(bfhi(w.x), vr, a1);
        a2 = fmaf(bflo(w.y), vr, a2); a3 = fmaf(bfhi(w.y), vr, a3);
        a4 = fmaf(bflo(w.z), vr, a4); a5 = fmaf(bfhi(w.z), vr, a5);
        a6 = fmaf(bflo(w.w), vr, a6); a7 = fmaf(bfhi(w.w), vr, a7);
    }
    float4* P = (float4*)(partials + (size_t)blockIdx.y * NH + (size_t)c8 * 8);
    float4 lo; lo.x=a0; lo.y=a1; lo.z=a2; lo.w=a3;
    float4 hi; hi.x=a4; hi.y=a5; hi.z=a6; hi.w=a7;
    P[0] = lo; P[1] = hi;
}

// h[j] = sigm(b[j] + sum_seg partials[seg][j]); optionally save hi. grid 16, block 256.
__global__ __launch_bounds__(256) void k_hreduce(const float* __restrict__ partials,
                                                 const float* __restrict__ b,
                                                 float* __restrict__ h,
                                                 float* __restrict__ hi) {
    int j = blockIdx.x * 256 + threadIdx.x;
    float s = 0.f;
    for (int g = 0; g < NSEG; ++g) s += partials[(size_t)g * NH + j];
    float hh = sigm(s + b[j]);
    h[j] = hh;
    if (hi) hi[j] = hh;
}

// v[row] = sigm(a[row] + Wbf[row,:].h). One wave per row. grid FLAT/4, block 256.
__global__ __launch_bounds__(256) void k_vstep_bf(const unsigned short* __restrict__ Wbf,
                                                  const float* __restrict__ h,
                                                  const float* __restrict__ a,
                                                  float* __restrict__ v) {
    int wid = threadIdx.x >> 6, lane = threadIdx.x & 63;
    int row = blockIdx.x * 4 + wid;
    const uint4* Wr = (const uint4*)(Wbf + (size_t)row * NH);
    const float4* h4 = (const float4*)h;
    float acc = 0.f;
    for (int k = lane; k < NH / 8; k += 64) {
        uint4 w = Wr[k];
        float4 ha = h4[2 * k], hb = h4[2 * k + 1];
        acc = fmaf(bflo(w.x), ha.x, acc); acc = fmaf(bfhi(w.x), ha.y, acc);
        acc = fmaf(bflo(w.y), ha.z, acc); acc = fmaf(bfhi(w.y), ha.w, acc);
        acc = fmaf(bflo(w.z), hb.x, acc); acc = fmaf(bfhi(w.z), hb.y, acc);
        acc = fmaf(bflo(w.w), hb.z, acc); acc = fmaf(bfhi(w.w), hb.w, acc);
    }
    acc = wave_sum63(acc);
    if (lane == 63) v[row] = sigm(a[row] + acc);
}

// fp32 fallback vstep. grid FLAT/4, block 256.
__global__ __launch_bounds__(256) void k_vstep_f32(const float* __restrict__ W,
                                                   const float* __restrict__ h,
                                                   const float* __restrict__ a,
                                                   float* __restrict__ v) {
    int wid = threadIdx.x >> 6, lane = threadIdx.x & 63;
    int row = blockIdx.x * 4 + wid;
    const float4* Wr = (const float4*)(W + (size_t)row * NH);
    const float4* h4 = (const float4*)h;
    float acc = 0.f;
    for (int k = lane; k < NH / 4; k += 64) {
        float4 w = Wr[k];
        float4 hh = h4[k];
        acc = fmaf(w.x, hh.x, fmaf(w.y, hh.y, fmaf(w.z, hh.z, fmaf(w.w, hh.w, acc))));
    }
    acc = wave_sum63(acc);
    if (lane == 63) v[row] = sigm(a[row] + acc);
}

// ================= Phase B =================

#define TB  512
#define RVB (FLAT / TB)   // 24
#define RHB (NH / TB)     // 8
#define NWAVES (TB / 64)  // 8

__global__ __launch_bounds__(512) void k_phaseB(const float* __restrict__ inputs,
                                                const float* __restrict__ hi0,
                                                const float* __restrict__ hk0,
                                                const float* __restrict__ vk0,
                                                float* __restrict__ out) {
    int t = threadIdx.x;
    int lane = t & 63, wid = t >> 6;
    __shared__ float2 red[2][NWAVES];

    float Vi[RVB], Vk[RVB], v[RVB];
    float Hi[RHB], Hk[RHB], h[RHB], hini[RHB];

#pragma unroll
    for (int r = 0; r < RVB; r++) { int i = r * TB + t; Vi[r] = inputs[i]; Vk[r] = vk0[i]; }
#pragma unroll
    for (int r = 0; r < RHB; r++) { int j = r * TB + t; Hi[r] = hi0[j]; Hk[r] = hk0[j]; }

    int rc = 0;
    for (int s = 1; s < 16; ++s) {
        const float* vin = inputs + (size_t)s * FLAT;
#pragma unroll
        for (int r = 0; r < RVB; r++) v[r] = vin[r * TB + t];

        for (int k = 0; k < KSTEPS; ++k) {
            // alpha = Vi.v, beta = Vk.v
            float px = 0.f, py = 0.f;
#pragma unroll
            for (int r = 0; r < RVB; r++) { px = fmaf(Vi[r], v[r], px); py = fmaf(Vk[r], v[r], py); }
            px = wave_sum63(px); py = wave_sum63(py);
            if (lane == 63) { float2 w2; w2.x = px; w2.y = py; red[rc & 1][wid] = w2; }
            __syncthreads();
            float al = 0.f, be = 0.f;
#pragma unroll
            for (int w = 0; w < NWAVES; w++) { float2 w2 = red[rc & 1][w]; al += w2.x; be += w2.y; }
            rc++;
            float ca = LRC * (1.f + al), cb = LRC * (1.f + be);

            // h = sigm(LR((1+al)Hi - (1+be)Hk)); gamma = Hi.h, delta = Hk.h
            float qx = 0.f, qy = 0.f;
#pragma unroll
            for (int r = 0; r < RHB; r++) {
                float hh = sigm(ca * Hi[r] - cb * Hk[r]);
                h[r] = hh;
                if (k == 0) hini[r] = hh;
                qx = fmaf(Hi[r], hh, qx); qy = fmaf(Hk[r], hh, qy);
            }
            qx = wave_sum63(qx); qy = wave_sum63(qy);
            if (lane == 63) { float2 w2; w2.x = qx; w2.y = qy; red[rc & 1][wid] = w2; }
            __syncthreads();
            float ga = 0.f, de = 0.f;
#pragma unroll
            for (int w = 0; w < NWAVES; w++) { float2 w2 = red[rc & 1][w]; ga += w2.x; de += w2.y; }
            rc++;
            float cg = LRC * (1.f + ga), cd = LRC * (1.f + de);

            // v = sigm(LR((1+ga)Vi - (1+de)Vk))
#pragma unroll
            for (int r = 0; r < RVB; r++) v[r] = sigm(cg * Vi[r] - cd * Vk[r]);
        }

        // rotate carry
#pragma unroll
        for (int r = 0; r < RVB; r++) { Vk[r] = v[r]; Vi[r] = vin[r * TB + t]; }
#pragma unroll
        for (int r = 0; r < RHB; r++) { Hk[r] = h[r]; Hi[r] = hini[r]; }
    }

#pragma unroll
    for (int r = 0; r < RVB; r++) out[r * TB + t] = Vk[r];
}

// ================= launch =================

extern "C" void kernel_launch(void* const* d_in, const int* in_sizes, int n_in,
                              void* d_out, int out_size, void* d_ws, size_t ws_size,
                              hipStream_t stream) {
    const float* inputs = (const float*)d_in[0];
    const float* W      = (const float*)d_in[1];
    const float* a_in   = (const float*)d_in[2];
    const float* b_in   = (const float*)d_in[3];
    float* out = (float*)d_out;

    const size_t WBF_BYTES = (size_t)FLAT * NH * sizeof(unsigned short);   // 96 MiB
    const size_t TAIL_FLOATS = (size_t)NSEG * NH + NH + NH + FLAT;
    bool use_bf16 = ws_size >= WBF_BYTES + TAIL_FLOATS * sizeof(float) + 256;

    dim3 blk(256);
    if (use_bf16) {
        unsigned short* Wbf = (unsigned short*)d_ws;
        float* partials = (float*)((char*)d_ws + WBF_BYTES);
        float* h  = partials + (size_t)NSEG * NH;
        float* hi = h + NH;
        float* v  = hi + NH;

        k_colpart_cvt<<<dim3(4, NSEG), blk, 0, stream>>>(W, inputs, partials, Wbf);
        k_hreduce<<<dim3(NH / 256), blk, 0, stream>>>(partials, b_in, h, hi);
        k_vstep_bf<<<dim3(FLAT / 4), blk, 0, stream>>>(Wbf, h, a_in, v);
        for (int k = 1; k < KSTEPS; ++k) {
            k_colpart_bf<<<dim3(2, NSEG), blk, 0, stream>>>(Wbf, v, partials);
            k_hreduce<<<dim3(NH / 256), blk, 0, stream>>>(partials, b_in, h, (float*)nullptr);
            k_vstep_bf<<<dim3(FLAT / 4), blk, 0, stream>>>(Wbf, h, a_in, v);
        }
        k_phaseB<<<1, TB, 0, stream>>>(inputs, hi, h, v, out);
    } else {
        float* partials = (float*)d_ws;
        float* h  = partials + (size_t)NSEG * NH;
        float* hi = h + NH;
        float* v  = hi + NH;

        k_colpart_f32<<<dim3(4, NSEG), blk, 0, stream>>>(W, inputs, partials);
        k_hreduce<<<dim3(NH / 256), blk, 0, stream>>>(partials, b_in, h, hi);
        k_vstep_f32<<<dim3(FLAT / 4), blk, 0, stream>>>(W, h, a_in, v);
        for (int k = 1; k < KSTEPS; ++k) {
            k_colpart_f32<<<dim3(4, NSEG), blk, 0, stream>>>(W, v, partials);
            k_hreduce<<<dim3(NH / 256), blk, 0, stream>>>(partials, b_in, h, (float*)nullptr);
            k_vstep_f32<<<dim3(FLAT / 4), blk, 0, stream>>>(W, h, a_in, v);
        }
        k_phaseB<<<1, TB, 0, stream>>>(inputs, hi, h, v, out);
    }
}

// Round 4
// 537.664 us; speedup vs baseline: 1.4887x; 1.0186x over previous
//
#include <hip/hip_runtime.h>
#include <math.h>

#define FLAT 12288
#define NH   4096
#define KSTEPS 4
#define LRC 0.01f
#define NSEG 384
#define RPS  32        // NSEG * RPS == FLAT
#define WSCALE 64.0f
#define WINV   0.015625f

typedef float v2f __attribute__((ext_vector_type(2)));

__device__ __forceinline__ float sigm(float x) {
    return __builtin_amdgcn_rcpf(1.0f + __expf(-x));
}

// ---- DPP wave64 sum: result valid in lane 63 ----
template <int CTRL>
__device__ __forceinline__ float dpp_add(float x) {
    int s = __builtin_amdgcn_update_dpp(0, __float_as_int(x), CTRL, 0xf, 0xf, true);
    return x + __int_as_float(s);
}
__device__ __forceinline__ float wave_sum63(float x) {
    x = dpp_add<0x111>(x);  // row_shr:1
    x = dpp_add<0x112>(x);  // row_shr:2
    x = dpp_add<0x114>(x);  // row_shr:4
    x = dpp_add<0x118>(x);  // row_shr:8
    x = dpp_add<0x142>(x);  // row_bcast:15
    x = dpp_add<0x143>(x);  // row_bcast:31
    return x;               // lane 63 holds the full sum
}

// ================= Phase A =================

// Pass 0: read fp32 W, emit column partials for h1, convert W -> fp8 (x64).
// grid (4, NSEG), block 256; 4 cols/thread.
__global__ __launch_bounds__(256) void k_colpart_cvt(const float* __restrict__ W,
                                                     const float* __restrict__ v,
                                                     float* __restrict__ partials,
                                                     unsigned int* __restrict__ W8) {
    const float4* W4 = (const float4*)W;
    int c4 = blockIdx.x * 256 + threadIdx.x;           // [0,1024)
    int r0 = blockIdx.y * RPS;
    float4 acc = make_float4(0.f, 0.f, 0.f, 0.f);
    for (int r = r0; r < r0 + RPS; ++r) {
        float vr = v[r];
        float4 w = W4[(size_t)r * (NH / 4) + c4];
        acc.x = fmaf(w.x, vr, acc.x);
        acc.y = fmaf(w.y, vr, acc.y);
        acc.z = fmaf(w.z, vr, acc.z);
        acc.w = fmaf(w.w, vr, acc.w);
        unsigned int p = 0;
        p = __builtin_amdgcn_cvt_pk_fp8_f32(w.x * WSCALE, w.y * WSCALE, p, false);
        p = __builtin_amdgcn_cvt_pk_fp8_f32(w.z * WSCALE, w.w * WSCALE, p, true);
        W8[(size_t)r * (NH / 4) + c4] = p;
    }
    ((float4*)partials)[(size_t)blockIdx.y * (NH / 4) + c4] = acc;
}

// fp8 colpart: 16 cols/thread (uint4 = 16 fp8). grid NSEG, block 256.
__global__ __launch_bounds__(256) void k_colpart_fp8(const uint4* __restrict__ W8,
                                                     const float* __restrict__ v,
                                                     float* __restrict__ partials) {
    int c16 = threadIdx.x;                              // [0,256)
    int r0 = blockIdx.x * RPS;
    float acc[16];
#pragma unroll
    for (int i = 0; i < 16; i++) acc[i] = 0.f;
    for (int r = r0; r < r0 + RPS; ++r) {
        float vr = v[r] * WINV;                         // fold descale into v
        uint4 w = W8[(size_t)r * (NH / 16) + c16];
        v2f f;
        f = __builtin_amdgcn_cvt_pk_f32_fp8(w.x, false); acc[0]  = fmaf(f.x, vr, acc[0]);  acc[1]  = fmaf(f.y, vr, acc[1]);
        f = __builtin_amdgcn_cvt_pk_f32_fp8(w.x, true);  acc[2]  = fmaf(f.x, vr, acc[2]);  acc[3]  = fmaf(f.y, vr, acc[3]);
        f = __builtin_amdgcn_cvt_pk_f32_fp8(w.y, false); acc[4]  = fmaf(f.x, vr, acc[4]);  acc[5]  = fmaf(f.y, vr, acc[5]);
        f = __builtin_amdgcn_cvt_pk_f32_fp8(w.y, true);  acc[6]  = fmaf(f.x, vr, acc[6]);  acc[7]  = fmaf(f.y, vr, acc[7]);
        f = __builtin_amdgcn_cvt_pk_f32_fp8(w.z, false); acc[8]  = fmaf(f.x, vr, acc[8]);  acc[9]  = fmaf(f.y, vr, acc[9]);
        f = __builtin_amdgcn_cvt_pk_f32_fp8(w.z, true);  acc[10] = fmaf(f.x, vr, acc[10]); acc[11] = fmaf(f.y, vr, acc[11]);
        f = __builtin_amdgcn_cvt_pk_f32_fp8(w.w, false); acc[12] = fmaf(f.x, vr, acc[12]); acc[13] = fmaf(f.y, vr, acc[13]);
        f = __builtin_amdgcn_cvt_pk_f32_fp8(w.w, true);  acc[14] = fmaf(f.x, vr, acc[14]); acc[15] = fmaf(f.y, vr, acc[15]);
    }
    float4* P = (float4*)(partials + (size_t)blockIdx.x * NH + (size_t)c16 * 16);
#pragma unroll
    for (int q = 0; q < 4; q++) {
        float4 o; o.x = acc[4*q]; o.y = acc[4*q+1]; o.z = acc[4*q+2]; o.w = acc[4*q+3];
        P[q] = o;
    }
}

// h[col] = sigm(b + sum over NSEG partials). grid NH/32, block 256 (32 cols x 8 seg-threads).
__global__ __launch_bounds__(256) void k_hreduce(const float* __restrict__ partials,
                                                 const float* __restrict__ b,
                                                 float* __restrict__ h,
                                                 float* __restrict__ hi) {
    int c  = threadIdx.x & 31;
    int sg = threadIdx.x >> 5;                          // 0..7
    int col = blockIdx.x * 32 + c;
    float s = 0.f;
    for (int g = sg; g < NSEG; g += 8) s += partials[(size_t)g * NH + col];
    __shared__ float red[8][33];
    red[sg][c] = s;
    __syncthreads();
    if (threadIdx.x < 32) {
        float t = 0.f;
#pragma unroll
        for (int g2 = 0; g2 < 8; g2++) t += red[g2][threadIdx.x];
        float hh = sigm(t + b[col]);
        h[col] = hh;
        if (hi) hi[col] = hh;
    }
}

// v[row] = sigm(a + W8[row,:].h / 64). One wave per row. grid FLAT/4, block 256.
__global__ __launch_bounds__(256) void k_vstep_fp8(const unsigned char* __restrict__ W8,
                                                   const float* __restrict__ h,
                                                   const float* __restrict__ a,
                                                   float* __restrict__ v) {
    int wid = threadIdx.x >> 6, lane = threadIdx.x & 63;
    int row = blockIdx.x * 4 + wid;
    const uint4* Wr = (const uint4*)(W8 + (size_t)row * NH);
    const float4* h4 = (const float4*)h;
    float acc = 0.f;
    for (int k = lane; k < NH / 16; k += 64) {          // 4 iters
        uint4 w = Wr[k];
        float4 h0 = h4[4*k], h1 = h4[4*k+1], h2 = h4[4*k+2], h3 = h4[4*k+3];
        v2f f;
        f = __builtin_amdgcn_cvt_pk_f32_fp8(w.x, false); acc = fmaf(f.x, h0.x, acc); acc = fmaf(f.y, h0.y, acc);
        f = __builtin_amdgcn_cvt_pk_f32_fp8(w.x, true);  acc = fmaf(f.x, h0.z, acc); acc = fmaf(f.y, h0.w, acc);
        f = __builtin_amdgcn_cvt_pk_f32_fp8(w.y, false); acc = fmaf(f.x, h1.x, acc); acc = fmaf(f.y, h1.y, acc);
        f = __builtin_amdgcn_cvt_pk_f32_fp8(w.y, true);  acc = fmaf(f.x, h1.z, acc); acc = fmaf(f.y, h1.w, acc);
        f = __builtin_amdgcn_cvt_pk_f32_fp8(w.z, false); acc = fmaf(f.x, h2.x, acc); acc = fmaf(f.y, h2.y, acc);
        f = __builtin_amdgcn_cvt_pk_f32_fp8(w.z, true);  acc = fmaf(f.x, h2.z, acc); acc = fmaf(f.y, h2.w, acc);
        f = __builtin_amdgcn_cvt_pk_f32_fp8(w.w, false); acc = fmaf(f.x, h3.x, acc); acc = fmaf(f.y, h3.y, acc);
        f = __builtin_amdgcn_cvt_pk_f32_fp8(w.w, true);  acc = fmaf(f.x, h3.z, acc); acc = fmaf(f.y, h3.w, acc);
    }
    acc = wave_sum63(acc);
    if (lane == 63) v[row] = sigm(a[row] + acc * WINV);
}

// ================= Phase B =================

#define TB  512
#define RVB (FLAT / TB)   // 24
#define RHB (NH / TB)     // 8
#define NWAVES (TB / 64)  // 8

__global__ __launch_bounds__(512) void k_phaseB(const float* __restrict__ inputs,
                                                const float* __restrict__ hi0,
                                                const float* __restrict__ hk0,
                                                const float* __restrict__ vk0,
                                                float* __restrict__ out) {
    int t = threadIdx.x;
    int lane = t & 63, wid = t >> 6;
    __shared__ float2 red[2][NWAVES];

    float Vi[RVB], Vk[RVB], v[RVB];
    float Hi[RHB], Hk[RHB], h[RHB], hini[RHB];

#pragma unroll
    for (int r = 0; r < RVB; r++) { int i = r * TB + t; Vi[r] = inputs[i]; Vk[r] = vk0[i]; }
#pragma unroll
    for (int r = 0; r < RHB; r++) { int j = r * TB + t; Hi[r] = hi0[j]; Hk[r] = hk0[j]; }

    int rc = 0;
    for (int s = 1; s < 16; ++s) {
        const float* vin = inputs + (size_t)s * FLAT;
#pragma unroll
        for (int r = 0; r < RVB; r++) v[r] = vin[r * TB + t];

        for (int k = 0; k < KSTEPS; ++k) {
            // alpha = Vi.v, beta = Vk.v  (2-way split chains)
            float px0 = 0.f, px1 = 0.f, py0 = 0.f, py1 = 0.f;
#pragma unroll
            for (int r = 0; r < RVB; r += 2) {
                px0 = fmaf(Vi[r],   v[r],   px0); py0 = fmaf(Vk[r],   v[r],   py0);
                px1 = fmaf(Vi[r+1], v[r+1], px1); py1 = fmaf(Vk[r+1], v[r+1], py1);
            }
            float px = wave_sum63(px0 + px1), py = wave_sum63(py0 + py1);
            if (lane == 63) { float2 w2; w2.x = px; w2.y = py; red[rc & 1][wid] = w2; }
            __syncthreads();
            float al = 0.f, be = 0.f;
#pragma unroll
            for (int w = 0; w < NWAVES; w++) { float2 w2 = red[rc & 1][w]; al += w2.x; be += w2.y; }
            rc++;
            float ca = LRC * (1.f + al), cb = LRC * (1.f + be);

            // h = sigm(LR((1+al)Hi - (1+be)Hk)); gamma = Hi.h, delta = Hk.h
            float qx = 0.f, qy = 0.f;
#pragma unroll
            for (int r = 0; r < RHB; r++) {
                float hh = sigm(ca * Hi[r] - cb * Hk[r]);
                h[r] = hh;
                if (k == 0) hini[r] = hh;
                qx = fmaf(Hi[r], hh, qx); qy = fmaf(Hk[r], hh, qy);
            }
            qx = wave_sum63(qx); qy = wave_sum63(qy);
            if (lane == 63) { float2 w2; w2.x = qx; w2.y = qy; red[rc & 1][wid] = w2; }
            __syncthreads();
            float ga = 0.f, de = 0.f;
#pragma unroll
            for (int w = 0; w < NWAVES; w++) { float2 w2 = red[rc & 1][w]; ga += w2.x; de += w2.y; }
            rc++;
            float cg = LRC * (1.f + ga), cd = LRC * (1.f + de);

            // v = sigm(LR((1+ga)Vi - (1+de)Vk))
#pragma unroll
            for (int r = 0; r < RVB; r++) v[r] = sigm(cg * Vi[r] - cd * Vk[r]);
        }

        // rotate carry
#pragma unroll
        for (int r = 0; r < RVB; r++) { Vk[r] = v[r]; Vi[r] = vin[r * TB + t]; }
#pragma unroll
        for (int r = 0; r < RHB; r++) { Hk[r] = h[r]; Hi[r] = hini[r]; }
    }

#pragma unroll
    for (int r = 0; r < RVB; r++) out[r * TB + t] = Vk[r];
}

// ================= launch =================

extern "C" void kernel_launch(void* const* d_in, const int* in_sizes, int n_in,
                              void* d_out, int out_size, void* d_ws, size_t ws_size,
                              hipStream_t stream) {
    const float* inputs = (const float*)d_in[0];
    const float* W      = (const float*)d_in[1];
    const float* a_in   = (const float*)d_in[2];
    const float* b_in   = (const float*)d_in[3];
    float* out = (float*)d_out;

    // ws layout: W8 (48 MiB) | partials (6 MiB) | h | hi | v   (ws_size >= 100 MiB per R3)
    unsigned int* W8 = (unsigned int*)d_ws;
    float* partials = (float*)((char*)d_ws + (size_t)FLAT * NH);
    float* h  = partials + (size_t)NSEG * NH;
    float* hi = h + NH;
    float* v  = hi + NH;

    dim3 blk(256);

    // Sample 0, Gibbs step 1 (h1 == h_init) + W -> fp8 conversion
    k_colpart_cvt<<<dim3(4, NSEG), blk, 0, stream>>>(W, inputs, partials, W8);
    k_hreduce<<<dim3(NH / 32), blk, 0, stream>>>(partials, b_in, h, hi);
    k_vstep_fp8<<<dim3(FLAT / 4), blk, 0, stream>>>((const unsigned char*)W8, h, a_in, v);

    // Gibbs steps 2..4
    for (int k = 1; k < KSTEPS; ++k) {
        k_colpart_fp8<<<dim3(NSEG), blk, 0, stream>>>((const uint4*)W8, v, partials);
        k_hreduce<<<dim3(NH / 32), blk, 0, stream>>>(partials, b_in, h, (float*)nullptr);
        k_vstep_fp8<<<dim3(FLAT / 4), blk, 0, stream>>>((const unsigned char*)W8, h, a_in, v);
    }

    // Samples 1..15 (rank-2 W), writes final reconstruction
    k_phaseB<<<1, TB, 0, stream>>>(inputs, hi, h, v, out);
}